// Round 2
// baseline (411.589 us; speedup 1.0000x reference)
//
#include <hip/hip_runtime.h>

// Problem constants
#define K_CODES 512
#define DIM 64
#define HW 1024          // 32*32 spatial per image
#define NVEC 65536       // 64 * 1024 flat vectors

// Output offsets (flat concat, reference return order)
#define O0 0             // loss (1)
#define O1 1             // out_q NCHW (4194304)
#define O2 4194305       // perplexity (1)
#define O3 4194306       // idx as float (65536)
#define O4 4259842       // new_cs (512)
#define O5 4260354       // new_ema_w (32768)
#define O6 4293122       // new_embedding (32768)

// Workspace layout (floats): [0]=loss accum, [64..576)=ee, [1024..1536)=counts(int), [2048..34816)=dw

__global__ void k0_init(const float* __restrict__ emb, float* __restrict__ wsf) {
    const int b = blockIdx.x, t = threadIdx.x;
    if (b < 128) {
        wsf[2048 + b * 256 + t] = 0.0f;                 // zero dw accumulator
    } else if (b == 128) {
        int* cnt = (int*)(wsf + 1024);
        cnt[t] = 0; cnt[t + 256] = 0;
        if (t == 0) wsf[0] = 0.0f;                      // zero loss accum
    } else {
        int k = (b - 129) * 256 + t;                    // 0..511
        const float* e = emb + k * DIM;
        float s = 0.0f;
        #pragma unroll
        for (int c = 0; c < DIM; ++c) s += e[c] * e[c];
        wsf[64 + k] = s;                                // ||e_k||^2
    }
}

// Block: 256 threads = 4 waves. 64 vectors/block; wave w scans codes [w*128, w*128+128).
// Grid 1024 -> 4 blocks/CU -> 4 waves/SIMD (latency hiding vs round-1's 1 wave/SIMD).
__global__ __launch_bounds__(256, 4)
void k1_main(const float* __restrict__ in, const float* __restrict__ emb,
             float* __restrict__ out, float* __restrict__ wsf) {
    __shared__ float xT[64 * 65];    // vector-major transpose, stride 65
    __shared__ float rd[256];        // per-thread best dist
    __shared__ int   ri[256];        // per-thread best idx; ri[0..63] reused for final idx
    __shared__ int   hist[K_CODES];

    const int t    = threadIdx.x;
    const int lane = t & 63;
    const int wave = t >> 6;                 // code-chunk id 0..3
    const int i    = blockIdx.x * 64 + lane; // flat vector index
    const int n    = i >> 10;
    const int hw   = i & 1023;

    hist[t] = 0; hist[t + 256] = 0;

    // Load x (coalesced per c-plane; all 4 waves load the same 64 vectors -> L1 hits)
    const float* xb = in + n * (DIM * HW) + hw;
    float x2[DIM];
    float xx = 0.0f;
    #pragma unroll
    for (int c = 0; c < DIM; ++c) {
        float v = xb[c * HW];
        xx += v * v;
        x2[c] = -2.0f * v;                   // fold the -2 into x
        if (wave == 0) xT[lane * 65 + c] = v;
    }

    // Distance + argmin over this wave's 128-code chunk.
    // d_k = ||e_k||^2 + dot(x2, e_k); accumulators init with ||e||^2 (scalar loads).
    const float* ee = wsf + 64;
    const int kbase = wave * 128;
    float best = 3.4e38f;
    int bidx = 0;
    for (int k = kbase; k < kbase + 128; k += 4) {
        const float* e0 = emb + k * DIM;     // wave-uniform -> s_load broadcast
        float d0 = ee[k], d1 = ee[k + 1], d2 = ee[k + 2], d3 = ee[k + 3];
        #pragma unroll
        for (int c = 0; c < DIM; ++c) {
            float xc = x2[c];
            d0 += xc * e0[c];
            d1 += xc * e0[c + 64];
            d2 += xc * e0[c + 128];
            d3 += xc * e0[c + 192];
        }
        if (d0 < best) { best = d0; bidx = k + 0; }   // strict <, ascending k ->
        if (d1 < best) { best = d1; bidx = k + 1; }   // first-min, matches argmin
        if (d2 < best) { best = d2; bidx = k + 2; }
        if (d3 < best) { best = d3; bidx = k + 3; }
    }
    rd[t] = best; ri[t] = bidx;
    __syncthreads();

    // Wave 0: cross-chunk argmin (ascending chunk order, strict < -> first-min),
    // loss partial, idx output, LDS histogram.
    if (wave == 0) {
        float bd = rd[lane];
        int   bi = ri[lane];
        #pragma unroll
        for (int w = 1; w < 4; ++w) {
            float d  = rd[w * 64 + lane];
            int   ii = ri[w * 64 + lane];
            if (d < bd) { bd = d; bi = ii; }
        }
        ri[lane] = bi;                        // publish final idx

        float ld = xx + bd;                   // d_min = xx + (ee - 2<x,e>)
        #pragma unroll
        for (int off = 32; off > 0; off >>= 1) ld += __shfl_down(ld, off);
        if (lane == 0) atomicAdd(wsf + 0, ld);

        out[O3 + i] = (float)bi;
        atomicAdd(&hist[bi], 1);
    }
    __syncthreads();

    // Epilogue parallelized over all 4 waves.
    // out_q: wave w writes c-planes [w*16, w*16+16) for all 64 vectors (coalesced).
    {
        int bi = ri[lane];
        const float* ew = emb + bi * DIM + wave * 16;
        float* oq = out + O1 + n * (DIM * HW) + hw + (wave * 16) * HW;
        #pragma unroll
        for (int c = 0; c < 16; ++c) oq[c * HW] = ew[c];
    }

    // dw: wave w handles vectors [w*16, w*16+16): coalesced 64-lane atomic row adds
    {
        float* dw = wsf + 2048;
        #pragma unroll 1
        for (int v = wave * 16; v < wave * 16 + 16; ++v) {
            int kv = ri[v];
            atomicAdd(&dw[kv * DIM + lane], xT[v * 65 + lane]);
        }
    }

    // flush histogram to global counts
    int* cnt = (int*)(wsf + 1024);
    if (hist[t])       atomicAdd(&cnt[t], hist[t]);
    if (hist[t + 256]) atomicAdd(&cnt[t + 256], hist[t + 256]);
}

__global__ void k2a(const float* __restrict__ ema_cs, float* __restrict__ out,
                    const float* __restrict__ wsf) {
    __shared__ float s1[512], s2[512];
    const int t = threadIdx.x;
    const int* cnt = (const int*)(wsf + 1024);
    float c   = (float)cnt[t];
    float raw = 0.99f * ema_cs[t] + 0.01f * c;
    float p   = c * (1.0f / 65536.0f);
    s1[t] = raw;
    s2[t] = p * logf(p + 1e-10f);
    __syncthreads();
    for (int s = 256; s > 0; s >>= 1) {
        if (t < s) { s1[t] += s1[t + s]; s2[t] += s2[t + s]; }
        __syncthreads();
    }
    float n = s1[0];
    float smooth = (raw + 1e-5f) / (n + 512.0f * 1e-5f) * n;   // Laplace smoothing
    out[O4 + t] = smooth;
    if (t == 0) {
        out[O2] = expf(-s2[0]);
        out[O0] = 0.25f * wsf[0] * (1.0f / 4194304.0f);        // BETA * mean
    }
}

__global__ void k2b(const float* __restrict__ ema_w, const float* __restrict__ wsf,
                    float* __restrict__ out) {
    const int m = blockIdx.x * 256 + threadIdx.x;   // 0..32767
    const int k = m >> 6;
    float w = 0.99f * ema_w[m] + 0.01f * wsf[2048 + m];
    out[O5 + m] = w;
    out[O6 + m] = w / out[O4 + k];                  // new_embedding = new_ema_w / new_cs
}

extern "C" void kernel_launch(void* const* d_in, const int* in_sizes, int n_in,
                              void* d_out, int out_size, void* d_ws, size_t ws_size,
                              hipStream_t stream) {
    const float* in     = (const float*)d_in[0];   // inputs  (64,64,32,32) NCHW
    const float* emb    = (const float*)d_in[1];   // embedding (512,64)
    const float* ema_w  = (const float*)d_in[2];   // ema_w (512,64)
    const float* ema_cs = (const float*)d_in[3];   // ema_cluster_size (512)
    float* out = (float*)d_out;
    float* wsf = (float*)d_ws;

    hipLaunchKernelGGL(k0_init, dim3(131),  dim3(256), 0, stream, emb, wsf);
    hipLaunchKernelGGL(k1_main, dim3(1024), dim3(256), 0, stream, in, emb, out, wsf);
    hipLaunchKernelGGL(k2a,     dim3(1),    dim3(512), 0, stream, ema_cs, out, wsf);
    hipLaunchKernelGGL(k2b,     dim3(128),  dim3(256), 0, stream, ema_w, wsf, out);
}

// Round 3
// 162.387 us; speedup vs baseline: 2.5346x; 2.5346x over previous
//
#include <hip/hip_runtime.h>

#define K_CODES 512
#define DIM 64
#define HW 1024
#define NVEC 65536

// Output offsets (flat concat, reference return order)
#define O0 0             // loss (1)
#define O1 1             // out_q NCHW (4194304)
#define O2 4194305       // perplexity (1)
#define O3 4194306       // idx as float (65536)
#define O4 4259842       // new_cs (512)
#define O5 4260354       // new_ema_w (32768)
#define O6 4293122       // new_embedding (32768)

// ws float layout: [0]=loss, [64..576)=ee, [1024..1536)=counts(int),
// [2048..34816)=dw, [35840..) = B-pack (98304 bf16 = 192KB, MFMA-frag order)
#define WS_EE  64
#define WS_CNT 1024
#define WS_DW  2048
#define WS_BP  35840
#define XSS    72        // padded LDS row stride (floats)

typedef __bf16 bf16x8 __attribute__((ext_vector_type(8)));
typedef float  f32x4  __attribute__((ext_vector_type(4)));

__global__ void k0_init(const float* __restrict__ emb, float* __restrict__ wsf) {
    const int b = blockIdx.x, t = threadIdx.x;
    if (b < 128) {
        wsf[WS_DW + b * 256 + t] = 0.0f;                 // zero dw accumulator
    } else if (b == 128) {
        int* cnt = (int*)(wsf + WS_CNT);
        cnt[t] = 0; cnt[t + 256] = 0;
        if (t == 0) wsf[0] = 0.0f;
    } else if (b < 131) {
        int k = (b - 129) * 256 + t;                     // 0..511
        const float* e = emb + k * DIM;
        float s = 0.0f;
        #pragma unroll
        for (int c = 0; c < DIM; ++c) s += e[c] * e[c];
        wsf[WS_EE + k] = s;                              // ||e_k||^2
    } else {
        // Pack bf16 3-way split of (-2*e) into MFMA B-fragment order:
        // frag(s, ntg, ks): lane l holds B^T[code = ntg*16 + (l&15)][c = ks*32 + (l>>4)*8 + j]
        int g = (b - 131) * 256 + t;                     // 0..98303
        int j    = g & 7;
        int lane = (g >> 3) & 63;
        int ks   = (g >> 9) & 1;
        int rest = g >> 10;                              // 0..95
        int ntg  = rest & 31;
        int s    = rest >> 5;                            // split 0..2
        int code = ntg * 16 + (lane & 15);
        int c    = ks * 32 + (lane >> 4) * 8 + j;
        float v = -2.0f * emb[code * DIM + c];
        __bf16 h0 = (__bf16)v;  float r1 = v  - (float)h0;
        __bf16 h1 = (__bf16)r1; float r2 = r1 - (float)h1;
        __bf16 hv = (s == 0) ? h0 : (s == 1 ? h1 : (__bf16)r2);
        ((__bf16*)(wsf + WS_BP))[g] = hv;
    }
}

// Block: 512 threads = 8 waves; 128 vectors x 512 codes per block.
// Wave (mi2 = w&1, ni2 = w>>1): 64-vector x 128-code tile = 4x8 MFMA 16x16 tiles.
__global__ __launch_bounds__(512, 2)
void k1_main(const float* __restrict__ in, const float* __restrict__ emb,
             float* __restrict__ out, float* __restrict__ wsf) {
    __shared__ float xs[128 * XSS];     // fp32 x tile, row=vector, col=c
    __shared__ float pmin[4][128];
    __shared__ int   pidx[4][128];
    __shared__ float xxs[128];
    __shared__ int   hist[K_CODES];

    const int t    = threadIdx.x;
    const int lane = t & 63;
    const int wave = t >> 6;           // 0..7
    const int mi2  = wave & 1;         // m half (64 vectors)
    const int ni2  = wave >> 1;        // n quarter (128 codes)
    const int col  = lane & 15;
    const int quad = lane >> 4;

    hist[t] = 0;

    const int blk     = blockIdx.x;
    const int n_img   = blk >> 3;
    const int hw_base = (blk & 7) * 128;
    const float* xbase = in + n_img * (DIM * HW) + hw_base;

    // Stage x: 128 vectors x 64 c, coalesced global reads
    #pragma unroll
    for (int rep = 0; rep < 16; ++rep) {
        int e = rep * 512 + t;
        int c = e >> 7, h0 = e & 127;
        xs[h0 * XSS + c] = xbase[c * HW + h0];
    }

    // Accumulators init with ||e||^2 (d = ee - 2<x,e>); all 4 rows share col's code
    f32x4 acc[4][8];
    #pragma unroll
    for (int nt = 0; nt < 8; ++nt) {
        float eev = wsf[WS_EE + ni2 * 128 + nt * 16 + col];
        #pragma unroll
        for (int mi = 0; mi < 4; ++mi) {
            acc[mi][nt][0] = eev; acc[mi][nt][1] = eev;
            acc[mi][nt][2] = eev; acc[mi][nt][3] = eev;
        }
    }

    __syncthreads();

    // ||x||^2 per vector (for loss only; argmin unaffected by +xx)
    if (t < 128) {
        float s = 0.0f;
        #pragma unroll
        for (int c = 0; c < DIM; ++c) { float v = xs[t * XSS + c]; s += v * v; }
        xxs[t] = s;
    }

    const bf16x8* bp8 = (const bf16x8*)(wsf + WS_BP);

    // K-loop: 2 k-steps x 6 split-pairs {(0,0),(1,0),(2,0),(0,1),(1,1),(0,2)}
    #pragma unroll
    for (int ks = 0; ks < 2; ++ks) {
        // Build A splits on the fly from fp32 LDS tile
        bf16x8 A0[4], A1[4], A2[4];
        #pragma unroll
        for (int mi = 0; mi < 4; ++mi) {
            const float* src = &xs[(mi2 * 64 + mi * 16 + col) * XSS + ks * 32 + quad * 8];
            #pragma unroll
            for (int j = 0; j < 8; ++j) {
                float v = src[j];
                __bf16 h0 = (__bf16)v;  float r1 = v  - (float)h0;
                __bf16 h1 = (__bf16)r1; float r2 = r1 - (float)h1;
                A0[mi][j] = h0; A1[mi][j] = h1; A2[mi][j] = (__bf16)r2;
            }
        }
        #pragma unroll
        for (int s = 0; s < 3; ++s) {
            bf16x8 Bv[8];
            #pragma unroll
            for (int nt = 0; nt < 8; ++nt)
                Bv[nt] = bp8[(((s * 32 + ni2 * 8 + nt) * 2 + ks) * 64) + lane];
            #pragma unroll
            for (int mi = 0; mi < 4; ++mi)
                #pragma unroll
                for (int nt = 0; nt < 8; ++nt)
                    acc[mi][nt] = __builtin_amdgcn_mfma_f32_16x16x32_bf16(A0[mi], Bv[nt], acc[mi][nt], 0, 0, 0);
            if (s < 2) {
                #pragma unroll
                for (int mi = 0; mi < 4; ++mi)
                    #pragma unroll
                    for (int nt = 0; nt < 8; ++nt)
                        acc[mi][nt] = __builtin_amdgcn_mfma_f32_16x16x32_bf16(A1[mi], Bv[nt], acc[mi][nt], 0, 0, 0);
            }
            if (s == 0) {
                #pragma unroll
                for (int mi = 0; mi < 4; ++mi)
                    #pragma unroll
                    for (int nt = 0; nt < 8; ++nt)
                        acc[mi][nt] = __builtin_amdgcn_mfma_f32_16x16x32_bf16(A2[mi], Bv[nt], acc[mi][nt], 0, 0, 0);
            }
        }
    }

    // Argmin. C layout: col(code) = lane&15, row(vector) = quad*4 + reg.
    #pragma unroll
    for (int mi = 0; mi < 4; ++mi) {
        #pragma unroll
        for (int r = 0; r < 4; ++r) {
            float v  = acc[mi][0][r];
            int   bi = ni2 * 128 + col;
            #pragma unroll
            for (int nt = 1; nt < 8; ++nt) {            // ascending codes, strict < = first-min
                float u  = acc[mi][nt][r];
                int   ui = ni2 * 128 + nt * 16 + col;
                if (u < v) { v = u; bi = ui; }
            }
            #pragma unroll
            for (int off = 1; off < 16; off <<= 1) {    // 16-lane butterfly, idx tie-break
                float ov = __shfl_xor(v, off);
                int   oi = __shfl_xor(bi, off);
                if (ov < v || (ov == v && oi < bi)) { v = ov; bi = oi; }
            }
            if (col == 0) {
                int row = mi2 * 64 + mi * 16 + quad * 4 + r;
                pmin[ni2][row] = v;
                pidx[ni2][row] = bi;
            }
        }
    }
    __syncthreads();

    // Combine the 4 n-quarters (ascending code ranges), then idx/loss/hist
    if (t < 128) {
        float v = pmin[0][t]; int bi = pidx[0][t];
        #pragma unroll
        for (int q = 1; q < 4; ++q) {
            float u = pmin[q][t]; int ui = pidx[q][t];
            if (u < v) { v = u; bi = ui; }
        }
        pidx[0][t] = bi;                                 // publish final idx
        out[O3 + blk * 128 + t] = (float)bi;
        atomicAdd(&hist[bi], 1);
        float ld = v + xxs[t];                           // d_min = xx + (ee - 2<x,e>)
        #pragma unroll
        for (int off = 32; off > 0; off >>= 1) ld += __shfl_down(ld, off);
        if ((t & 63) == 0) atomicAdd(wsf + 0, ld);
    }
    __syncthreads();

    // out_q: thread t -> vector v = t&127, c-quarter t>>7; writes coalesced per c-plane
    {
        int v = t & 127, cq = t >> 7;
        int kv = pidx[0][v];
        const float* ew = emb + kv * DIM;
        float* oq = out + O1 + n_img * (DIM * HW) + hw_base + v;
        #pragma unroll
        for (int c = cq * 16; c < cq * 16 + 16; ++c) oq[c * HW] = ew[c];
    }

    // dw: wave w -> vectors [w*16, w*16+16): coalesced 64-lane atomic row adds
    {
        float* dw = wsf + WS_DW;
        #pragma unroll 1
        for (int v = wave * 16; v < wave * 16 + 16; ++v) {
            int kv = pidx[0][v];
            atomicAdd(&dw[kv * DIM + lane], xs[v * XSS + lane]);
        }
    }

    int* cnt = (int*)(wsf + WS_CNT);
    if (hist[t]) atomicAdd(&cnt[t], hist[t]);
}

__global__ void k2a(const float* __restrict__ ema_cs, float* __restrict__ out,
                    const float* __restrict__ wsf) {
    __shared__ float s1[512], s2[512];
    const int t = threadIdx.x;
    const int* cnt = (const int*)(wsf + WS_CNT);
    float c   = (float)cnt[t];
    float raw = 0.99f * ema_cs[t] + 0.01f * c;
    float p   = c * (1.0f / 65536.0f);
    s1[t] = raw;
    s2[t] = p * logf(p + 1e-10f);
    __syncthreads();
    for (int s = 256; s > 0; s >>= 1) {
        if (t < s) { s1[t] += s1[t + s]; s2[t] += s2[t + s]; }
        __syncthreads();
    }
    float n = s1[0];
    float smooth = (raw + 1e-5f) / (n + 512.0f * 1e-5f) * n;   // Laplace smoothing
    out[O4 + t] = smooth;
    if (t == 0) {
        out[O2] = expf(-s2[0]);
        out[O0] = 0.25f * wsf[0] * (1.0f / 4194304.0f);        // BETA * mean
    }
}

__global__ void k2b(const float* __restrict__ ema_w, const float* __restrict__ wsf,
                    float* __restrict__ out) {
    const int m = blockIdx.x * 256 + threadIdx.x;   // 0..32767
    const int k = m >> 6;
    float w = 0.99f * ema_w[m] + 0.01f * wsf[WS_DW + m];
    out[O5 + m] = w;
    out[O6 + m] = w / out[O4 + k];                  // new_embedding = new_ema_w / new_cs
}

extern "C" void kernel_launch(void* const* d_in, const int* in_sizes, int n_in,
                              void* d_out, int out_size, void* d_ws, size_t ws_size,
                              hipStream_t stream) {
    const float* in     = (const float*)d_in[0];   // inputs  (64,64,32,32) NCHW
    const float* emb    = (const float*)d_in[1];   // embedding (512,64)
    const float* ema_w  = (const float*)d_in[2];   // ema_w (512,64)
    const float* ema_cs = (const float*)d_in[3];   // ema_cluster_size (512)
    float* out = (float*)d_out;
    float* wsf = (float*)d_ws;

    hipLaunchKernelGGL(k0_init, dim3(515), dim3(256), 0, stream, emb, wsf);
    hipLaunchKernelGGL(k1_main, dim3(512), dim3(512), 0, stream, in, emb, out, wsf);
    hipLaunchKernelGGL(k2a,     dim3(1),   dim3(512), 0, stream, ema_cs, out, wsf);
    hipLaunchKernelGGL(k2b,     dim3(128), dim3(256), 0, stream, ema_w, wsf, out);
}